// Round 20
// baseline (85.324 us; speedup 1.0000x reference)
//
#include <hip/hip_runtime.h>
#include <hip/hip_bf16.h>
#include <stdint.h>

#define S_LEN 2048
#define D_DIM 64
#define BH    64
#define NQT   16          // q-tiles of 128 rows
#define LOG2E 1.44269504088896f
#define THR   8.0f
#define TEN_ELEMS (BH * S_LEN * D_DIM)

typedef __attribute__((ext_vector_type(8)))  short bf16x8;
typedef __attribute__((ext_vector_type(4)))  short s16x4;
typedef __attribute__((ext_vector_type(4)))  float f32x4;
typedef __attribute__((ext_vector_type(16))) float f32x16;
typedef __attribute__((ext_vector_type(4)))  uint32_t u32x4;

__device__ __forceinline__ short f2bf(float f) {
    uint32_t u = __builtin_bit_cast(uint32_t, f);
    u += 0x7FFFu + ((u >> 16) & 1u);   // RNE
    return (short)(u >> 16);
}

// packed f32->bf16 (emits v_cvt_pk_bf16_f32); memcpy because __hip_bfloat162
// is not trivially copyable.
__device__ __forceinline__ uint32_t pkbf(float lo, float hi) {
    __hip_bfloat162 h = __float22bfloat162_rn(make_float2(lo, hi));
    uint32_t r;
    __builtin_memcpy(&r, &h, 4);
    return r;
}

__device__ __forceinline__ float xhalf_max(float v) {
    return fmaxf(v, __shfl_xor(v, 32));
}
__device__ __forceinline__ float xhalf_sum(float v) {
    return v + __shfl_xor(v, 32);
}

// XOR swizzle on short-index of a [rows][64]-short tile (byte bits 4..6).
__device__ __forceinline__ int swz(int row, int col) {
    return (row * 64 + col) ^ ((row & 7) << 3);
}

#if __has_builtin(__builtin_amdgcn_exp2f)
#define EXP2(x) __builtin_amdgcn_exp2f(x)
#else
#define EXP2(x) exp2f(x)
#endif

// async global->LDS, 16B per lane; LDS dest = wave-uniform base + lane*16.
typedef __attribute__((address_space(1))) const uint32_t glb_u32;
typedef __attribute__((address_space(3))) uint32_t lds_u32;
__device__ __forceinline__ void llds16(const short* g, short* l) {
    __builtin_amdgcn_global_load_lds((glb_u32*)g, (lds_u32*)l, 16, 0, 0);
}

// non-temporal f32x4 load — ONLY the hot kernel's Q prologue (zero reuse,
// latency hidden under STAGE(0) DMA; keeps image L2 set resident).
// NOT in prep (R18: prep 4.9->23us with NT) and NOT on Out stores
// (R19: total +7us — NT-store drain showed up as inter-kernel gap).
__device__ __forceinline__ f32x4 ntload4(const float* p) {
    return __builtin_nontemporal_load((const f32x4*)p);
}

// ============================ pre-pass kernel ============================
// ws layout (shorts):
//   Kimg [0, 8.4M)       per-64x64-tile LDS images, XOR-swizzled
//   Vimg [8.4M, 16.8M)   per-tile images: transposed + quad-permuted + swizzled
__global__ __launch_bounds__(256)
void prep_kv(const float* __restrict__ K, const float* __restrict__ V,
             short* __restrict__ Kimg, short* __restrict__ Vimg)
{
    const int kt = blockIdx.x;              // kv tile 0..31
    const int bh = blockIdx.y;
    const int tid = threadIdx.x;

    // ---- K image: row-major bf16 at swz(row, d) ----
    {
        const float* Kp = K + ((size_t)bh * S_LEN + (size_t)kt * 64) * D_DIM;
        short* Ko = Kimg + ((size_t)bh * 32 + kt) * 4096;
        const int row = tid >> 2, d0 = (tid & 3) * 16;
        const float* src = Kp + row * D_DIM + d0;
        f32x4 a = *(const f32x4*)(src);
        f32x4 b = *(const f32x4*)(src + 4);
        f32x4 c = *(const f32x4*)(src + 8);
        f32x4 d = *(const f32x4*)(src + 12);
        bf16x8 w0, w1;
        #pragma unroll
        for (int j = 0; j < 4; ++j) {
            w0[j] = f2bf(a[j]); w0[4 + j] = f2bf(b[j]);
            w1[j] = f2bf(c[j]); w1[4 + j] = f2bf(d[j]);
        }
        *(bf16x8*)&Ko[swz(row, d0)]     = w0;
        *(bf16x8*)&Ko[swz(row, d0 + 8)] = w1;
    }

    // ---- V image: V[kv][d] -> swz(d, sigma(kv)); sigma = quad 1<->2 per
    // 16-kv group (hot-loop PV A-fragment becomes a straight pack, R11) ----
    {
        const float* Vp = V + ((size_t)bh * S_LEN + (size_t)kt * 64) * D_DIM;
        short* Vo = Vimg + ((size_t)bh * 32 + kt) * 4096;
        __shared__ short T[64][72];         // +8 pad
        const int row = tid >> 2, q4 = tid & 3;
        #pragma unroll
        for (int j = 0; j < 4; ++j) {
            f32x4 v = *(const f32x4*)(Vp + row * D_DIM + q4 * 16 + j * 4);
            #pragma unroll
            for (int e = 0; e < 4; ++e) T[row][q4 * 16 + j * 4 + e] = f2bf(v[e]);
        }
        __syncthreads();
        const int d = tid >> 2, kq = tid & 3;
        #pragma unroll
        for (int j = 0; j < 4; ++j) {
            s16x4 w;
            #pragma unroll
            for (int e = 0; e < 4; ++e) w[e] = T[kq * 16 + j * 4 + e][d];
            const int jd = (j == 1) ? 2 : ((j == 2) ? 1 : j);   // quad 1 <-> 2
            *(s16x4*)&Vo[swz(d, kq * 16 + jd * 4)] = w;
        }
    }
}

// ============================ hot kernel ============================
// staging = pure linear 8KB image copy per tensor: 2 global_load_lds
// dwordx4 issues per wave per tensor.
#define STAGE(kb, buf) do { \
    const short* ks_ = Kimg + ((size_t)bh * 32 + (kb)) * 4096; \
    const short* vs_ = Vimg + ((size_t)bh * 32 + (kb)) * 4096; \
    const int wo_ = wid * 1024; \
    llds16(ks_ + wo_ + lane * 8,       &Kl[buf][wo_]); \
    llds16(ks_ + wo_ + 512 + lane * 8, &Kl[buf][wo_ + 512]); \
    llds16(vs_ + wo_ + lane * 8,       &Vl[buf][wo_]); \
    llds16(vs_ + wo_ + 512 + lane * 8, &Vl[buf][wo_ + 512]); \
} while (0)

// PV A-fragment: straight pack of the lane's 8 P-values (V rows pre-permuted).
#define MKFRAG(dst, sv, R0) do { \
    u32x4 t_; \
    t_[0] = pkbf(sv[(R0)+0], sv[(R0)+1]); \
    t_[1] = pkbf(sv[(R0)+2], sv[(R0)+3]); \
    t_[2] = pkbf(sv[(R0)+4], sv[(R0)+5]); \
    t_[3] = pkbf(sv[(R0)+6], sv[(R0)+7]); \
    dst = __builtin_bit_cast(bf16x8, t_); \
} while (0)

#define PVSTEP(pa, koff, acc0, acc1, b) do { \
    bf16x8 vf0_ = *(const bf16x8*)&Vl[b][swz(lq32,      (koff) + hi * 8)]; \
    bf16x8 vf1_ = *(const bf16x8*)&Vl[b][swz(32 + lq32, (koff) + hi * 8)]; \
    acc0 = __builtin_amdgcn_mfma_f32_32x32x16_bf16(pa, vf0_, acc0, 0, 0, 0); \
    acc1 = __builtin_amdgcn_mfma_f32_32x32x16_bf16(pa, vf1_, acc1, 0, 0, 0); \
} while (0)

// Swapped QK^T with 32x32x16: S^T[kv][q]; lane: q = lq32,
// kv = kvsub*32 + (r&3) + 8*(r>>2) + 4*hi.  Softmax fully in-lane + 1 xhalf.
#define COMPUTE32(qf, acc0, acc1, mm, ll, q0, kv0, b) do { \
    f32x16 s0_ = (f32x16)0.f, s1_ = (f32x16)0.f; \
    __builtin_amdgcn_s_setprio(1); \
    _Pragma("unroll") for (int c = 0; c < 4; ++c) { \
        bf16x8 k0_ = *(const bf16x8*)&Kl[b][swz(lq32,      c * 16 + hi * 8)]; \
        bf16x8 k1_ = *(const bf16x8*)&Kl[b][swz(32 + lq32, c * 16 + hi * 8)]; \
        s0_ = __builtin_amdgcn_mfma_f32_32x32x16_bf16(k0_, qf[c], s0_, 0, 0, 0); \
        s1_ = __builtin_amdgcn_mfma_f32_32x32x16_bf16(k1_, qf[c], s1_, 0, 0, 0); \
    } \
    __builtin_amdgcn_s_setprio(0); \
    if ((kv0) + 63 > (q0)) {   /* diagonal tile: causal mask */ \
        _Pragma("unroll") for (int r = 0; r < 16; ++r) { \
            const int kvr_ = (r & 3) + 8 * (r >> 2) + 4 * hi; \
            if ((kv0) + kvr_      > (q0) + lq32) s0_[r] = -1e30f; \
            if ((kv0) + 32 + kvr_ > (q0) + lq32) s1_[r] = -1e30f; \
        } \
    } \
    float m0_ = fmaxf(s0_[0], s1_[0]), m1_ = fmaxf(s0_[1], s1_[1]); \
    float m2_ = fmaxf(s0_[2], s1_[2]), m3_ = fmaxf(s0_[3], s1_[3]); \
    _Pragma("unroll") for (int r = 4; r < 16; r += 4) { \
        m0_ = fmaxf(m0_, fmaxf(s0_[r],     s1_[r])); \
        m1_ = fmaxf(m1_, fmaxf(s0_[r + 1], s1_[r + 1])); \
        m2_ = fmaxf(m2_, fmaxf(s0_[r + 2], s1_[r + 2])); \
        m3_ = fmaxf(m3_, fmaxf(s0_[r + 3], s1_[r + 3])); \
    } \
    float pmax_ = xhalf_max(fmaxf(fmaxf(m0_, m1_), fmaxf(m2_, m3_))); \
    if (!__all(pmax_ <= (mm) + THR)) {      /* defer-max: rare rescale */ \
        const float mn_ = fmaxf((mm), pmax_); \
        const float f_  = EXP2((mm) - mn_); \
        (ll) *= f_; \
        _Pragma("unroll") for (int r = 0; r < 16; ++r) { \
            const float fr_ = __shfl(f_, (r & 3) + 8 * (r >> 2) + 4 * hi); \
            acc0[r] *= fr_; acc1[r] *= fr_; \
        } \
        (mm) = mn_; \
    } \
    float t0_ = 0.f, t1_ = 0.f, t2_ = 0.f, t3_ = 0.f; \
    _Pragma("unroll") for (int r = 0; r < 16; r += 4) { \
        s0_[r]     = EXP2(s0_[r]     - (mm)); s1_[r]     = EXP2(s1_[r]     - (mm)); \
        s0_[r + 1] = EXP2(s0_[r + 1] - (mm)); s1_[r + 1] = EXP2(s1_[r + 1] - (mm)); \
        s0_[r + 2] = EXP2(s0_[r + 2] - (mm)); s1_[r + 2] = EXP2(s1_[r + 2] - (mm)); \
        s0_[r + 3] = EXP2(s0_[r + 3] - (mm)); s1_[r + 3] = EXP2(s1_[r + 3] - (mm)); \
        t0_ += s0_[r]     + s1_[r]; \
        t1_ += s0_[r + 1] + s1_[r + 1]; \
        t2_ += s0_[r + 2] + s1_[r + 2]; \
        t3_ += s0_[r + 3] + s1_[r + 3]; \
    } \
    (ll) += (t0_ + t1_) + (t2_ + t3_);      /* in-lane half-sum; combine at end */ \
    bf16x8 pa0_, pa1_, pa2_, pa3_; \
    MKFRAG(pa0_, s0_, 0); MKFRAG(pa1_, s0_, 8); \
    MKFRAG(pa2_, s1_, 0); MKFRAG(pa3_, s1_, 8); \
    __builtin_amdgcn_s_setprio(1); \
    PVSTEP(pa0_, 0,  acc0, acc1, b); \
    PVSTEP(pa1_, 16, acc0, acc1, b); \
    PVSTEP(pa2_, 32, acc0, acc1, b); \
    PVSTEP(pa3_, 48, acc0, acc1, b); \
    __builtin_amdgcn_s_setprio(0); \
} while (0)

// R14/R16 grid geometry: bh fast dim -> XCD k (id mod 8) sees only
// bh = k (mod 8): 8 bh x 512KB images = 4MB = one XCD L2.
// qt = 15 - blockIdx.y -> heavy q-tiles dispatch first (LPT schedule).
__global__ __launch_bounds__(256, 2)
void attn_fwd_bf16(const float* __restrict__ Q, const short* __restrict__ Kimg,
                   const short* __restrict__ Vimg, float* __restrict__ Out)
{
    const int bh   = blockIdx.x;           // 0..63 (fast dim)
    const int qt   = NQT - 1 - blockIdx.y; // heavy-first
    const int tid  = threadIdx.x;
    const int wid  = tid >> 6;             // 0..3
    const int lane = tid & 63;
    const int lq32 = lane & 31;
    const int hi   = lane >> 5;

    const int nkv = 2 * qt + 2;            // 64-wide kv tiles

    float* Op = Out + (size_t)bh * S_LEN * D_DIM;

    __shared__ __align__(16) short Kl[2][64 * 64];
    __shared__ __align__(16) short Vl[2][64 * 64];

    const int q0 = qt * 128 + wid * 32;

    // ---- prologue: issue Q loads (non-temporal, issued FIRST so their HBM
    // latency hides under the STAGE(0) DMA), then stage, then convert ----
    f32x4 qx[8];
    {
        const float* qp = Q + ((size_t)bh * S_LEN + (size_t)(q0 + lq32)) * D_DIM;
        #pragma unroll
        for (int c = 0; c < 4; ++c) {
            qx[2 * c]     = ntload4(qp + c * 16 + hi * 8);
            qx[2 * c + 1] = ntload4(qp + c * 16 + hi * 8 + 4);
        }
    }
    STAGE(0, 0);
    bf16x8 qf[4];
    {
        const float sc = 0.125f * LOG2E;
        #pragma unroll
        for (int c = 0; c < 4; ++c) {
            #pragma unroll
            for (int j = 0; j < 4; ++j) {
                qf[c][j]     = f2bf(qx[2 * c][j] * sc);
                qf[c][4 + j] = f2bf(qx[2 * c + 1][j] * sc);
            }
        }
    }

    f32x16 acc0 = (f32x16)0.f, acc1 = (f32x16)0.f;
    float m = -1e30f, l = 0.f;

    __syncthreads();                        // vmcnt drained: tile 0 resident

    for (int j = 0; j < nkv; ++j) {
        const int  buf  = j & 1;
        const bool more = (j + 1) < nkv;
        if (more) STAGE(j + 1, buf ^ 1);    // DMA flies under compute
        if (j * 64 <= q0 + 31) COMPUTE32(qf, acc0, acc1, m, l, q0, j * 64, buf);
        if (more) __syncthreads();          // drains DMA; frees buf for j+2
    }

    // ---- epilogue: combine half-sums, O = acc / l (normal stores —
    // NT stores moved drain cost into the inter-kernel gap, R19) ----
    l = xhalf_sum(l);
    const float il = 1.f / l;
    #pragma unroll
    for (int r = 0; r < 16; ++r) {
        const int qr   = (r & 3) + 8 * (r >> 2) + 4 * hi;
        const float vl = __shfl(il, qr);
        Op[(size_t)(q0 + qr) * D_DIM + lq32]      = acc0[r] * vl;
        Op[(size_t)(q0 + qr) * D_DIM + 32 + lq32] = acc1[r] * vl;
    }
}

extern "C" void kernel_launch(void* const* d_in, const int* in_sizes, int n_in,
                              void* d_out, int out_size, void* d_ws, size_t ws_size,
                              hipStream_t stream) {
    const float* q = (const float*)d_in[0];
    const float* k = (const float*)d_in[1];
    const float* v = (const float*)d_in[2];
    // d_in[3] (causal tril mask) handled analytically.
    float* out = (float*)d_out;
    (void)in_sizes; (void)n_in; (void)out_size; (void)ws_size;

    // ws: Kimg + Vimg per-tile LDS images (33.6 MB)
    short* Kimg = (short*)d_ws;
    short* Vimg = Kimg + TEN_ELEMS;
    prep_kv<<<dim3(S_LEN / 64, BH), 256, 0, stream>>>(k, v, Kimg, Vimg);
    attn_fwd_bf16<<<dim3(BH, NQT), 256, 0, stream>>>(q, Kimg, Vimg, out);
}

// Round 21
// 82.657 us; speedup vs baseline: 1.0323x; 1.0323x over previous
//
#include <hip/hip_runtime.h>
#include <hip/hip_bf16.h>
#include <stdint.h>

#define S_LEN 2048
#define D_DIM 64
#define BH    64
#define NQT   16          // q-tiles of 128 rows
#define LOG2E 1.44269504088896f
#define THR   8.0f
#define TEN_ELEMS (BH * S_LEN * D_DIM)

typedef __attribute__((ext_vector_type(8)))  short bf16x8;
typedef __attribute__((ext_vector_type(4)))  short s16x4;
typedef __attribute__((ext_vector_type(4)))  float f32x4;
typedef __attribute__((ext_vector_type(16))) float f32x16;
typedef __attribute__((ext_vector_type(4)))  uint32_t u32x4;

__device__ __forceinline__ short f2bf(float f) {
    uint32_t u = __builtin_bit_cast(uint32_t, f);
    u += 0x7FFFu + ((u >> 16) & 1u);   // RNE
    return (short)(u >> 16);
}

// packed f32->bf16 (emits v_cvt_pk_bf16_f32); memcpy because __hip_bfloat162
// is not trivially copyable.
__device__ __forceinline__ uint32_t pkbf(float lo, float hi) {
    __hip_bfloat162 h = __float22bfloat162_rn(make_float2(lo, hi));
    uint32_t r;
    __builtin_memcpy(&r, &h, 4);
    return r;
}

__device__ __forceinline__ float xhalf_max(float v) {
    return fmaxf(v, __shfl_xor(v, 32));
}
__device__ __forceinline__ float xhalf_sum(float v) {
    return v + __shfl_xor(v, 32);
}

// XOR swizzle on short-index of a [rows][64]-short tile (byte bits 4..6).
__device__ __forceinline__ int swz(int row, int col) {
    return (row * 64 + col) ^ ((row & 7) << 3);
}

#if __has_builtin(__builtin_amdgcn_exp2f)
#define EXP2(x) __builtin_amdgcn_exp2f(x)
#else
#define EXP2(x) exp2f(x)
#endif

// async global->LDS, 16B per lane; LDS dest = wave-uniform base + lane*16.
typedef __attribute__((address_space(1))) const uint32_t glb_u32;
typedef __attribute__((address_space(3))) uint32_t lds_u32;
__device__ __forceinline__ void llds16(const short* g, short* l) {
    __builtin_amdgcn_global_load_lds((glb_u32*)g, (lds_u32*)l, 16, 0, 0);
}

// ============================ pre-pass kernel ============================
// ws layout (shorts):
//   Kimg [0, 8.4M)       per-64x64-tile LDS images, XOR-swizzled
//   Vimg [8.4M, 16.8M)   per-tile images: transposed + quad-permuted + swizzled
// (Q is read fp32 directly by the hot kernel — Qb round-trip is net negative
//  (R16/R17); non-temporal hints anywhere are net negative on total
//  (R18/R19/R20) despite improving the hot dispatch.)
__global__ __launch_bounds__(256)
void prep_kv(const float* __restrict__ K, const float* __restrict__ V,
             short* __restrict__ Kimg, short* __restrict__ Vimg)
{
    const int kt = blockIdx.x;              // kv tile 0..31
    const int bh = blockIdx.y;
    const int tid = threadIdx.x;

    // ---- K image: row-major bf16 at swz(row, d) ----
    {
        const float* Kp = K + ((size_t)bh * S_LEN + (size_t)kt * 64) * D_DIM;
        short* Ko = Kimg + ((size_t)bh * 32 + kt) * 4096;
        const int row = tid >> 2, d0 = (tid & 3) * 16;
        const float* src = Kp + row * D_DIM + d0;
        f32x4 a = *(const f32x4*)(src);
        f32x4 b = *(const f32x4*)(src + 4);
        f32x4 c = *(const f32x4*)(src + 8);
        f32x4 d = *(const f32x4*)(src + 12);
        bf16x8 w0, w1;
        #pragma unroll
        for (int j = 0; j < 4; ++j) {
            w0[j] = f2bf(a[j]); w0[4 + j] = f2bf(b[j]);
            w1[j] = f2bf(c[j]); w1[4 + j] = f2bf(d[j]);
        }
        *(bf16x8*)&Ko[swz(row, d0)]     = w0;
        *(bf16x8*)&Ko[swz(row, d0 + 8)] = w1;
    }

    // ---- V image: V[kv][d] -> swz(d, sigma(kv)); sigma = quad 1<->2 per
    // 16-kv group (hot-loop PV A-fragment becomes a straight pack, R11) ----
    {
        const float* Vp = V + ((size_t)bh * S_LEN + (size_t)kt * 64) * D_DIM;
        short* Vo = Vimg + ((size_t)bh * 32 + kt) * 4096;
        __shared__ short T[64][72];         // +8 pad
        const int row = tid >> 2, q4 = tid & 3;
        #pragma unroll
        for (int j = 0; j < 4; ++j) {
            f32x4 v = *(const f32x4*)(Vp + row * D_DIM + q4 * 16 + j * 4);
            #pragma unroll
            for (int e = 0; e < 4; ++e) T[row][q4 * 16 + j * 4 + e] = f2bf(v[e]);
        }
        __syncthreads();
        const int d = tid >> 2, kq = tid & 3;
        #pragma unroll
        for (int j = 0; j < 4; ++j) {
            s16x4 w;
            #pragma unroll
            for (int e = 0; e < 4; ++e) w[e] = T[kq * 16 + j * 4 + e][d];
            const int jd = (j == 1) ? 2 : ((j == 2) ? 1 : j);   // quad 1 <-> 2
            *(s16x4*)&Vo[swz(d, kq * 16 + jd * 4)] = w;
        }
    }
}

// ============================ hot kernel ============================
// staging = pure linear 8KB image copy per tensor: 2 global_load_lds
// dwordx4 issues per wave per tensor.
#define STAGE(kb, buf) do { \
    const short* ks_ = Kimg + ((size_t)bh * 32 + (kb)) * 4096; \
    const short* vs_ = Vimg + ((size_t)bh * 32 + (kb)) * 4096; \
    const int wo_ = wid * 1024; \
    llds16(ks_ + wo_ + lane * 8,       &Kl[buf][wo_]); \
    llds16(ks_ + wo_ + 512 + lane * 8, &Kl[buf][wo_ + 512]); \
    llds16(vs_ + wo_ + lane * 8,       &Vl[buf][wo_]); \
    llds16(vs_ + wo_ + 512 + lane * 8, &Vl[buf][wo_ + 512]); \
} while (0)

// PV A-fragment: straight pack of the lane's 8 P-values (V rows pre-permuted).
#define MKFRAG(dst, sv, R0) do { \
    u32x4 t_; \
    t_[0] = pkbf(sv[(R0)+0], sv[(R0)+1]); \
    t_[1] = pkbf(sv[(R0)+2], sv[(R0)+3]); \
    t_[2] = pkbf(sv[(R0)+4], sv[(R0)+5]); \
    t_[3] = pkbf(sv[(R0)+6], sv[(R0)+7]); \
    dst = __builtin_bit_cast(bf16x8, t_); \
} while (0)

#define PVSTEP(pa, koff, acc0, acc1, b) do { \
    bf16x8 vf0_ = *(const bf16x8*)&Vl[b][swz(lq32,      (koff) + hi * 8)]; \
    bf16x8 vf1_ = *(const bf16x8*)&Vl[b][swz(32 + lq32, (koff) + hi * 8)]; \
    acc0 = __builtin_amdgcn_mfma_f32_32x32x16_bf16(pa, vf0_, acc0, 0, 0, 0); \
    acc1 = __builtin_amdgcn_mfma_f32_32x32x16_bf16(pa, vf1_, acc1, 0, 0, 0); \
} while (0)

// Swapped QK^T with 32x32x16: S^T[kv][q]; lane: q = lq32,
// kv = kvsub*32 + (r&3) + 8*(r>>2) + 4*hi.  Softmax fully in-lane + 1 xhalf.
#define COMPUTE32(qf, acc0, acc1, mm, ll, q0, kv0, b) do { \
    f32x16 s0_ = (f32x16)0.f, s1_ = (f32x16)0.f; \
    __builtin_amdgcn_s_setprio(1); \
    _Pragma("unroll") for (int c = 0; c < 4; ++c) { \
        bf16x8 k0_ = *(const bf16x8*)&Kl[b][swz(lq32,      c * 16 + hi * 8)]; \
        bf16x8 k1_ = *(const bf16x8*)&Kl[b][swz(32 + lq32, c * 16 + hi * 8)]; \
        s0_ = __builtin_amdgcn_mfma_f32_32x32x16_bf16(k0_, qf[c], s0_, 0, 0, 0); \
        s1_ = __builtin_amdgcn_mfma_f32_32x32x16_bf16(k1_, qf[c], s1_, 0, 0, 0); \
    } \
    __builtin_amdgcn_s_setprio(0); \
    if ((kv0) + 63 > (q0)) {   /* diagonal tile: causal mask */ \
        _Pragma("unroll") for (int r = 0; r < 16; ++r) { \
            const int kvr_ = (r & 3) + 8 * (r >> 2) + 4 * hi; \
            if ((kv0) + kvr_      > (q0) + lq32) s0_[r] = -1e30f; \
            if ((kv0) + 32 + kvr_ > (q0) + lq32) s1_[r] = -1e30f; \
        } \
    } \
    float m0_ = fmaxf(s0_[0], s1_[0]), m1_ = fmaxf(s0_[1], s1_[1]); \
    float m2_ = fmaxf(s0_[2], s1_[2]), m3_ = fmaxf(s0_[3], s1_[3]); \
    _Pragma("unroll") for (int r = 4; r < 16; r += 4) { \
        m0_ = fmaxf(m0_, fmaxf(s0_[r],     s1_[r])); \
        m1_ = fmaxf(m1_, fmaxf(s0_[r + 1], s1_[r + 1])); \
        m2_ = fmaxf(m2_, fmaxf(s0_[r + 2], s1_[r + 2])); \
        m3_ = fmaxf(m3_, fmaxf(s0_[r + 3], s1_[r + 3])); \
    } \
    float pmax_ = xhalf_max(fmaxf(fmaxf(m0_, m1_), fmaxf(m2_, m3_))); \
    if (!__all(pmax_ <= (mm) + THR)) {      /* defer-max: rare rescale */ \
        const float mn_ = fmaxf((mm), pmax_); \
        const float f_  = EXP2((mm) - mn_); \
        (ll) *= f_; \
        _Pragma("unroll") for (int r = 0; r < 16; ++r) { \
            const float fr_ = __shfl(f_, (r & 3) + 8 * (r >> 2) + 4 * hi); \
            acc0[r] *= fr_; acc1[r] *= fr_; \
        } \
        (mm) = mn_; \
    } \
    float t0_ = 0.f, t1_ = 0.f, t2_ = 0.f, t3_ = 0.f; \
    _Pragma("unroll") for (int r = 0; r < 16; r += 4) { \
        s0_[r]     = EXP2(s0_[r]     - (mm)); s1_[r]     = EXP2(s1_[r]     - (mm)); \
        s0_[r + 1] = EXP2(s0_[r + 1] - (mm)); s1_[r + 1] = EXP2(s1_[r + 1] - (mm)); \
        s0_[r + 2] = EXP2(s0_[r + 2] - (mm)); s1_[r + 2] = EXP2(s1_[r + 2] - (mm)); \
        s0_[r + 3] = EXP2(s0_[r + 3] - (mm)); s1_[r + 3] = EXP2(s1_[r + 3] - (mm)); \
        t0_ += s0_[r]     + s1_[r]; \
        t1_ += s0_[r + 1] + s1_[r + 1]; \
        t2_ += s0_[r + 2] + s1_[r + 2]; \
        t3_ += s0_[r + 3] + s1_[r + 3]; \
    } \
    (ll) += (t0_ + t1_) + (t2_ + t3_);      /* in-lane half-sum; combine at end */ \
    bf16x8 pa0_, pa1_, pa2_, pa3_; \
    MKFRAG(pa0_, s0_, 0); MKFRAG(pa1_, s0_, 8); \
    MKFRAG(pa2_, s1_, 0); MKFRAG(pa3_, s1_, 8); \
    __builtin_amdgcn_s_setprio(1); \
    PVSTEP(pa0_, 0,  acc0, acc1, b); \
    PVSTEP(pa1_, 16, acc0, acc1, b); \
    PVSTEP(pa2_, 32, acc0, acc1, b); \
    PVSTEP(pa3_, 48, acc0, acc1, b); \
    __builtin_amdgcn_s_setprio(0); \
} while (0)

// Grid geometry: bh fast dim -> flattened id = bh + 64*qtIdx, so XCD k
// (id mod 8) sees only bh = k (mod 8): 8 bh x 512KB images = 4MB = one
// XCD L2 -> KV reads L2-resident.  qt = 15 - blockIdx.y -> heavy q-tiles
// dispatch first (LPT schedule).  This exact configuration measured
// 82.4us total (R16) — the session minimum on the graded metric.
__global__ __launch_bounds__(256, 2)
void attn_fwd_bf16(const float* __restrict__ Q, const short* __restrict__ Kimg,
                   const short* __restrict__ Vimg, float* __restrict__ Out)
{
    const int bh   = blockIdx.x;           // 0..63 (fast dim)
    const int qt   = NQT - 1 - blockIdx.y; // heavy-first
    const int tid  = threadIdx.x;
    const int wid  = tid >> 6;             // 0..3
    const int lane = tid & 63;
    const int lq32 = lane & 31;
    const int hi   = lane >> 5;

    const int nkv = 2 * qt + 2;            // 64-wide kv tiles

    float* Op = Out + (size_t)bh * S_LEN * D_DIM;

    __shared__ __align__(16) short Kl[2][64 * 64];
    __shared__ __align__(16) short Vl[2][64 * 64];

    const int q0 = qt * 128 + wid * 32;

    // Q fragments direct from fp32 (B-operand): col q = lq32, k(d) = c*16+hi*8+j
    bf16x8 qf[4];
    {
        const float sc = 0.125f * LOG2E;
        const float* qp = Q + ((size_t)bh * S_LEN + (size_t)(q0 + lq32)) * D_DIM;
        #pragma unroll
        for (int c = 0; c < 4; ++c) {
            f32x4 x0 = *(const f32x4*)(qp + c * 16 + hi * 8);
            f32x4 x1 = *(const f32x4*)(qp + c * 16 + hi * 8 + 4);
            #pragma unroll
            for (int j = 0; j < 4; ++j) {
                qf[c][j]     = f2bf(x0[j] * sc);
                qf[c][4 + j] = f2bf(x1[j] * sc);
            }
        }
    }

    f32x16 acc0 = (f32x16)0.f, acc1 = (f32x16)0.f;
    float m = -1e30f, l = 0.f;

    STAGE(0, 0);
    __syncthreads();                        // vmcnt drained: tile 0 resident

    for (int j = 0; j < nkv; ++j) {
        const int  buf  = j & 1;
        const bool more = (j + 1) < nkv;
        if (more) STAGE(j + 1, buf ^ 1);    // DMA flies under compute
        if (j * 64 <= q0 + 31) COMPUTE32(qf, acc0, acc1, m, l, q0, j * 64, buf);
        if (more) __syncthreads();          // drains DMA; frees buf for j+2
    }

    // ---- epilogue: combine half-sums, O = acc / l ----
    l = xhalf_sum(l);
    const float il = 1.f / l;
    #pragma unroll
    for (int r = 0; r < 16; ++r) {
        const int qr   = (r & 3) + 8 * (r >> 2) + 4 * hi;
        const float vl = __shfl(il, qr);
        Op[(size_t)(q0 + qr) * D_DIM + lq32]      = acc0[r] * vl;
        Op[(size_t)(q0 + qr) * D_DIM + 32 + lq32] = acc1[r] * vl;
    }
}

extern "C" void kernel_launch(void* const* d_in, const int* in_sizes, int n_in,
                              void* d_out, int out_size, void* d_ws, size_t ws_size,
                              hipStream_t stream) {
    const float* q = (const float*)d_in[0];
    const float* k = (const float*)d_in[1];
    const float* v = (const float*)d_in[2];
    // d_in[3] (causal tril mask) handled analytically.
    float* out = (float*)d_out;
    (void)in_sizes; (void)n_in; (void)out_size; (void)ws_size;

    // ws: Kimg + Vimg per-tile LDS images (33.6 MB)
    short* Kimg = (short*)d_ws;
    short* Vimg = Kimg + TEN_ELEMS;
    prep_kv<<<dim3(S_LEN / 64, BH), 256, 0, stream>>>(k, v, Kimg, Vimg);
    attn_fwd_bf16<<<dim3(BH, NQT), 256, 0, stream>>>(q, Kimg, Vimg, out);
}

// Round 22
// 80.457 us; speedup vs baseline: 1.0605x; 1.0274x over previous
//
#include <hip/hip_runtime.h>
#include <hip/hip_bf16.h>
#include <stdint.h>

#define S_LEN 2048
#define D_DIM 64
#define BH    64
#define NQT   16          // q-tiles of 128 rows
#define LOG2E 1.44269504088896f
#define THR   8.0f
#define TEN_ELEMS (BH * S_LEN * D_DIM)

typedef __attribute__((ext_vector_type(8)))  short bf16x8;
typedef __attribute__((ext_vector_type(4)))  short s16x4;
typedef __attribute__((ext_vector_type(4)))  float f32x4;
typedef __attribute__((ext_vector_type(16))) float f32x16;
typedef __attribute__((ext_vector_type(4)))  uint32_t u32x4;

__device__ __forceinline__ short f2bf(float f) {
    uint32_t u = __builtin_bit_cast(uint32_t, f);
    u += 0x7FFFu + ((u >> 16) & 1u);   // RNE
    return (short)(u >> 16);
}

__device__ __forceinline__ uint32_t pkbf(float lo, float hi) {
    __hip_bfloat162 h = __float22bfloat162_rn(make_float2(lo, hi));
    uint32_t r;
    __builtin_memcpy(&r, &h, 4);
    return r;
}

__device__ __forceinline__ float xhalf_max(float v) {
    return fmaxf(v, __shfl_xor(v, 32));
}
__device__ __forceinline__ float xhalf_sum(float v) {
    return v + __shfl_xor(v, 32);
}

// XOR swizzle on short-index of a [rows][64]-short tile (byte bits 4..6).
__device__ __forceinline__ int swz(int row, int col) {
    return (row * 64 + col) ^ ((row & 7) << 3);
}

#if __has_builtin(__builtin_amdgcn_exp2f)
#define EXP2(x) __builtin_amdgcn_exp2f(x)
#else
#define EXP2(x) exp2f(x)
#endif

// async global->LDS, 16B per lane; LDS dest = wave-uniform base + lane*16.
typedef __attribute__((address_space(1))) const uint32_t glb_u32;
typedef __attribute__((address_space(3))) uint32_t lds_u32;
__device__ __forceinline__ void llds16(const short* g, short* l) {
    __builtin_amdgcn_global_load_lds((glb_u32*)g, (lds_u32*)l, 16, 0, 0);
}

// T4 counted-vmcnt primitives: raw barrier (no implicit vmcnt(0) drain)
// and literal-count vmcnt waits.  sched_barrier + "memory" clobber pin
// ordering (rule #18 class: compiler may otherwise move LDS ops across).
#define WAIT4() asm volatile("s_waitcnt vmcnt(4)" ::: "memory")
#define WAIT0() asm volatile("s_waitcnt vmcnt(0)" ::: "memory")
#define RAWBAR() do { \
    __builtin_amdgcn_sched_barrier(0); \
    __builtin_amdgcn_s_barrier(); \
    __builtin_amdgcn_sched_barrier(0); \
} while (0)

// ============================ pre-pass kernel ============================
// ws layout (shorts):
//   Kimg [0, 8.4M)       per-64x64-tile LDS images, XOR-swizzled
//   Vimg [8.4M, 16.8M)   per-tile images: transposed + quad-permuted + swizzled
__global__ __launch_bounds__(256)
void prep_kv(const float* __restrict__ K, const float* __restrict__ V,
             short* __restrict__ Kimg, short* __restrict__ Vimg)
{
    const int kt = blockIdx.x;              // kv tile 0..31
    const int bh = blockIdx.y;
    const int tid = threadIdx.x;

    // ---- K image: row-major bf16 at swz(row, d) ----
    {
        const float* Kp = K + ((size_t)bh * S_LEN + (size_t)kt * 64) * D_DIM;
        short* Ko = Kimg + ((size_t)bh * 32 + kt) * 4096;
        const int row = tid >> 2, d0 = (tid & 3) * 16;
        const float* src = Kp + row * D_DIM + d0;
        f32x4 a = *(const f32x4*)(src);
        f32x4 b = *(const f32x4*)(src + 4);
        f32x4 c = *(const f32x4*)(src + 8);
        f32x4 d = *(const f32x4*)(src + 12);
        bf16x8 w0, w1;
        #pragma unroll
        for (int j = 0; j < 4; ++j) {
            w0[j] = f2bf(a[j]); w0[4 + j] = f2bf(b[j]);
            w1[j] = f2bf(c[j]); w1[4 + j] = f2bf(d[j]);
        }
        *(bf16x8*)&Ko[swz(row, d0)]     = w0;
        *(bf16x8*)&Ko[swz(row, d0 + 8)] = w1;
    }

    // ---- V image: V[kv][d] -> swz(d, sigma(kv)); sigma = quad 1<->2 per
    // 16-kv group (hot-loop PV A-fragment becomes a straight pack, R11) ----
    {
        const float* Vp = V + ((size_t)bh * S_LEN + (size_t)kt * 64) * D_DIM;
        short* Vo = Vimg + ((size_t)bh * 32 + kt) * 4096;
        __shared__ short T[64][72];         // +8 pad
        const int row = tid >> 2, q4 = tid & 3;
        #pragma unroll
        for (int j = 0; j < 4; ++j) {
            f32x4 v = *(const f32x4*)(Vp + row * D_DIM + q4 * 16 + j * 4);
            #pragma unroll
            for (int e = 0; e < 4; ++e) T[row][q4 * 16 + j * 4 + e] = f2bf(v[e]);
        }
        __syncthreads();
        const int d = tid >> 2, kq = tid & 3;
        #pragma unroll
        for (int j = 0; j < 4; ++j) {
            s16x4 w;
            #pragma unroll
            for (int e = 0; e < 4; ++e) w[e] = T[kq * 16 + j * 4 + e][d];
            const int jd = (j == 1) ? 2 : ((j == 2) ? 1 : j);   // quad 1 <-> 2
            *(s16x4*)&Vo[swz(d, kq * 16 + jd * 4)] = w;
        }
    }
}

// ============================ hot kernel ============================
// staging = pure linear 8KB image copy per tensor: 4 global_load_lds
// dwordx4 issues per wave (counts 4 against vmcnt).
#define STAGE(kb, buf) do { \
    const short* ks_ = Kimg + ((size_t)bh * 32 + (kb)) * 4096; \
    const short* vs_ = Vimg + ((size_t)bh * 32 + (kb)) * 4096; \
    const int wo_ = wid * 1024; \
    llds16(ks_ + wo_ + lane * 8,       &Kl[buf][wo_]); \
    llds16(ks_ + wo_ + 512 + lane * 8, &Kl[buf][wo_ + 512]); \
    llds16(vs_ + wo_ + lane * 8,       &Vl[buf][wo_]); \
    llds16(vs_ + wo_ + 512 + lane * 8, &Vl[buf][wo_ + 512]); \
} while (0)

// PV A-fragment: straight pack of the lane's 8 P-values (V rows pre-permuted).
#define MKFRAG(dst, sv, R0) do { \
    u32x4 t_; \
    t_[0] = pkbf(sv[(R0)+0], sv[(R0)+1]); \
    t_[1] = pkbf(sv[(R0)+2], sv[(R0)+3]); \
    t_[2] = pkbf(sv[(R0)+4], sv[(R0)+5]); \
    t_[3] = pkbf(sv[(R0)+6], sv[(R0)+7]); \
    dst = __builtin_bit_cast(bf16x8, t_); \
} while (0)

#define PVSTEP(pa, koff, acc0, acc1, b) do { \
    bf16x8 vf0_ = *(const bf16x8*)&Vl[b][swz(lq32,      (koff) + hi * 8)]; \
    bf16x8 vf1_ = *(const bf16x8*)&Vl[b][swz(32 + lq32, (koff) + hi * 8)]; \
    acc0 = __builtin_amdgcn_mfma_f32_32x32x16_bf16(pa, vf0_, acc0, 0, 0, 0); \
    acc1 = __builtin_amdgcn_mfma_f32_32x32x16_bf16(pa, vf1_, acc1, 0, 0, 0); \
} while (0)

// Swapped QK^T with 32x32x16: S^T[kv][q]; lane: q = lq32,
// kv = kvsub*32 + (r&3) + 8*(r>>2) + 4*hi.  Softmax fully in-lane + 1 xhalf.
#define COMPUTE32(qf, acc0, acc1, mm, ll, q0, kv0, b) do { \
    f32x16 s0_ = (f32x16)0.f, s1_ = (f32x16)0.f; \
    __builtin_amdgcn_s_setprio(1); \
    _Pragma("unroll") for (int c = 0; c < 4; ++c) { \
        bf16x8 k0_ = *(const bf16x8*)&Kl[b][swz(lq32,      c * 16 + hi * 8)]; \
        bf16x8 k1_ = *(const bf16x8*)&Kl[b][swz(32 + lq32, c * 16 + hi * 8)]; \
        s0_ = __builtin_amdgcn_mfma_f32_32x32x16_bf16(k0_, qf[c], s0_, 0, 0, 0); \
        s1_ = __builtin_amdgcn_mfma_f32_32x32x16_bf16(k1_, qf[c], s1_, 0, 0, 0); \
    } \
    __builtin_amdgcn_s_setprio(0); \
    if ((kv0) + 63 > (q0)) {   /* diagonal tile: causal mask */ \
        _Pragma("unroll") for (int r = 0; r < 16; ++r) { \
            const int kvr_ = (r & 3) + 8 * (r >> 2) + 4 * hi; \
            if ((kv0) + kvr_      > (q0) + lq32) s0_[r] = -1e30f; \
            if ((kv0) + 32 + kvr_ > (q0) + lq32) s1_[r] = -1e30f; \
        } \
    } \
    float m0_ = fmaxf(s0_[0], s1_[0]), m1_ = fmaxf(s0_[1], s1_[1]); \
    float m2_ = fmaxf(s0_[2], s1_[2]), m3_ = fmaxf(s0_[3], s1_[3]); \
    _Pragma("unroll") for (int r = 4; r < 16; r += 4) { \
        m0_ = fmaxf(m0_, fmaxf(s0_[r],     s1_[r])); \
        m1_ = fmaxf(m1_, fmaxf(s0_[r + 1], s1_[r + 1])); \
        m2_ = fmaxf(m2_, fmaxf(s0_[r + 2], s1_[r + 2])); \
        m3_ = fmaxf(m3_, fmaxf(s0_[r + 3], s1_[r + 3])); \
    } \
    float pmax_ = xhalf_max(fmaxf(fmaxf(m0_, m1_), fmaxf(m2_, m3_))); \
    if (!__all(pmax_ <= (mm) + THR)) {      /* defer-max: rare rescale */ \
        const float mn_ = fmaxf((mm), pmax_); \
        const float f_  = EXP2((mm) - mn_); \
        (ll) *= f_; \
        _Pragma("unroll") for (int r = 0; r < 16; ++r) { \
            const float fr_ = __shfl(f_, (r & 3) + 8 * (r >> 2) + 4 * hi); \
            acc0[r] *= fr_; acc1[r] *= fr_; \
        } \
        (mm) = mn_; \
    } \
    float t0_ = 0.f, t1_ = 0.f, t2_ = 0.f, t3_ = 0.f; \
    _Pragma("unroll") for (int r = 0; r < 16; r += 4) { \
        s0_[r]     = EXP2(s0_[r]     - (mm)); s1_[r]     = EXP2(s1_[r]     - (mm)); \
        s0_[r + 1] = EXP2(s0_[r + 1] - (mm)); s1_[r + 1] = EXP2(s1_[r + 1] - (mm)); \
        s0_[r + 2] = EXP2(s0_[r + 2] - (mm)); s1_[r + 2] = EXP2(s1_[r + 2] - (mm)); \
        s0_[r + 3] = EXP2(s0_[r + 3] - (mm)); s1_[r + 3] = EXP2(s1_[r + 3] - (mm)); \
        t0_ += s0_[r]     + s1_[r]; \
        t1_ += s0_[r + 1] + s1_[r + 1]; \
        t2_ += s0_[r + 2] + s1_[r + 2]; \
        t3_ += s0_[r + 3] + s1_[r + 3]; \
    } \
    (ll) += (t0_ + t1_) + (t2_ + t3_);      /* in-lane half-sum; combine at end */ \
    bf16x8 pa0_, pa1_, pa2_, pa3_; \
    MKFRAG(pa0_, s0_, 0); MKFRAG(pa1_, s0_, 8); \
    MKFRAG(pa2_, s1_, 0); MKFRAG(pa3_, s1_, 8); \
    __builtin_amdgcn_s_setprio(1); \
    PVSTEP(pa0_, 0,  acc0, acc1, b); \
    PVSTEP(pa1_, 16, acc0, acc1, b); \
    PVSTEP(pa2_, 32, acc0, acc1, b); \
    PVSTEP(pa3_, 48, acc0, acc1, b); \
    __builtin_amdgcn_s_setprio(0); \
} while (0)

// Grid geometry (R16-proven): bh fast dim -> XCD k (id mod 8) sees only
// bh = k (mod 8): 8 bh x 512KB images = 4MB = one XCD L2.  qt heavy-first.
// T4 counted-vmcnt loop: 2-deep prefetch, raw barriers, never drain vmcnt
// to 0 in steady state — tile j+2's DMA stays in flight across barriers.
__global__ __launch_bounds__(256, 2)
void attn_fwd_bf16(const float* __restrict__ Q, const short* __restrict__ Kimg,
                   const short* __restrict__ Vimg, float* __restrict__ Out)
{
    const int bh   = blockIdx.x;           // 0..63 (fast dim)
    const int qt   = NQT - 1 - blockIdx.y; // heavy-first
    const int tid  = threadIdx.x;
    const int wid  = tid >> 6;             // 0..3
    const int lane = tid & 63;
    const int lq32 = lane & 31;
    const int hi   = lane >> 5;

    const int nkv = 2 * qt + 2;            // 64-wide kv tiles (>= 2 always)

    float* Op = Out + (size_t)bh * S_LEN * D_DIM;

    __shared__ __align__(16) short Kl[2][64 * 64];
    __shared__ __align__(16) short Vl[2][64 * 64];

    const int q0 = qt * 128 + wid * 32;

    // Q fragments direct from fp32 (B-operand): col q = lq32, k(d) = c*16+hi*8+j
    bf16x8 qf[4];
    {
        const float sc = 0.125f * LOG2E;
        const float* qp = Q + ((size_t)bh * S_LEN + (size_t)(q0 + lq32)) * D_DIM;
        #pragma unroll
        for (int c = 0; c < 4; ++c) {
            f32x4 x0 = *(const f32x4*)(qp + c * 16 + hi * 8);
            f32x4 x1 = *(const f32x4*)(qp + c * 16 + hi * 8 + 4);
            #pragma unroll
            for (int j = 0; j < 4; ++j) {
                qf[c][j]     = f2bf(x0[j] * sc);
                qf[c][4 + j] = f2bf(x1[j] * sc);
            }
        }
    }

    f32x16 acc0 = (f32x16)0.f, acc1 = (f32x16)0.f;
    float m = -1e30f, l = 0.f;

    // ---- prologue: 2-deep prefetch; wait only for tile 0 (4 oldest) ----
    STAGE(0, 0);
    STAGE(1, 1);
    WAIT4();                                // tile 0 landed (tile 1 in flight)
    RAWBAR();                               // all waves' tile-0 portions visible

    for (int j = 0; j < nkv; ++j) {
        const int buf = j & 1;
        if (j * 64 <= q0 + 31) COMPUTE32(qf, acc0, acc1, m, l, q0, j * 64, buf);
        if (j + 1 < nkv) {
            RAWBAR();                       // all waves done reading buf
            if (j + 2 < nkv) {
                STAGE(j + 2, buf);          // overwrite buf (safe post-barrier)
                WAIT4();                    // tile j+1 landed; j+2 still flying
            } else {
                WAIT0();                    // tail: drain tile j+1
            }
            RAWBAR();                       // tile j+1 visible to all waves
        }
    }

    // ---- epilogue: combine half-sums, O = acc / l ----
    l = xhalf_sum(l);
    const float il = 1.f / l;
    #pragma unroll
    for (int r = 0; r < 16; ++r) {
        const int qr   = (r & 3) + 8 * (r >> 2) + 4 * hi;
        const float vl = __shfl(il, qr);
        Op[(size_t)(q0 + qr) * D_DIM + lq32]      = acc0[r] * vl;
        Op[(size_t)(q0 + qr) * D_DIM + 32 + lq32] = acc1[r] * vl;
    }
}

extern "C" void kernel_launch(void* const* d_in, const int* in_sizes, int n_in,
                              void* d_out, int out_size, void* d_ws, size_t ws_size,
                              hipStream_t stream) {
    const float* q = (const float*)d_in[0];
    const float* k = (const float*)d_in[1];
    const float* v = (const float*)d_in[2];
    // d_in[3] (causal tril mask) handled analytically.
    float* out = (float*)d_out;
    (void)in_sizes; (void)n_in; (void)out_size; (void)ws_size;

    // ws: Kimg + Vimg per-tile LDS images (33.6 MB)
    short* Kimg = (short*)d_ws;
    short* Vimg = Kimg + TEN_ELEMS;
    prep_kv<<<dim3(S_LEN / 64, BH), 256, 0, stream>>>(k, v, Kimg, Vimg);
    attn_fwd_bf16<<<dim3(BH, NQT), 256, 0, stream>>>(q, Kimg, Vimg, out);
}